// Round 8
// baseline (71.267 us; speedup 1.0000x reference)
//
#include <hip/hip_runtime.h>

typedef __attribute__((ext_vector_type(8))) short   bf16x8;
typedef __attribute__((ext_vector_type(4))) float   f32x4;
typedef __attribute__((ext_vector_type(4))) unsigned int u32x4;

#define HT 8           // output rows per block (both kernels)
#define XT_W 130       // padded pixel stride: col 0 and col 129 are zero

__device__ __forceinline__ unsigned short f2bf(float f) {
    union { float f; unsigned u; } v; v.f = f;
    unsigned u = v.u;
    u += 0x7FFFu + ((u >> 16) & 1u);   // RNE
    return (unsigned short)(u >> 16);
}

// ---------------------------------------------------------------------------
// Pre-pass: x (N=32, C=32, H=128, W=128) f32 NCHW -> x_t (N,H,130,32) bf16.
// Grid (16,2,32) == main kernel's grid -> same linear-index %8 -> the SAME
// XCD that writes an x_t region later reads it in the conv (L2-local).
// Block (hb,wh,n) converts rows hb*8..hb*8+7, w-half wh.
// ---------------------------------------------------------------------------
__global__ __launch_bounds__(256, 4)
void nchw_to_nhwc_bf16(const float* __restrict__ x, unsigned short* __restrict__ xt) {
    const int hb = blockIdx.x, wh = blockIdx.y, n = blockIdx.z;
    const int tid = threadIdx.x;
    const int cb = tid >> 6, w = tid & 63;       // c-octet, w within 64
    const int wg = wh * 64 + w;

    __shared__ u32x4 tile[2][64 * 5];            // [w][cb] padded stride 5

    const float* p0 = x + (((size_t)(n * 32 + cb * 8) * 128) * 128) + wg;
    u32x4* dst = (u32x4*)xt;

    #pragma unroll
    for (int i = 0; i < 8; ++i) {
        const int h = hb * 8 + i;
        const float* p = p0 + h * 128;
        float v[8];
        #pragma unroll
        for (int j = 0; j < 8; ++j) v[j] = p[j * 16384];
        u32x4 pk;
        pk[0] = (unsigned)f2bf(v[0]) | ((unsigned)f2bf(v[1]) << 16);
        pk[1] = (unsigned)f2bf(v[2]) | ((unsigned)f2bf(v[3]) << 16);
        pk[2] = (unsigned)f2bf(v[4]) | ((unsigned)f2bf(v[5]) << 16);
        pk[3] = (unsigned)f2bf(v[6]) | ((unsigned)f2bf(v[7]) << 16);
        tile[i & 1][w * 5 + cb] = pk;
        __syncthreads();
        // contiguous write: thread tid emits 16B for (pixel tid>>2, octet tid&3)
        const int base = ((n * 128 + h) * XT_W + 1 + wh * 64) * 4;
        dst[base + tid] = tile[i & 1][(tid >> 2) * 5 + (tid & 3)];
        // zero border columns (p=0 by wh==0 blocks, p=129 by wh==1)
        if (tid < 4) {
            const u32x4 z = {0u, 0u, 0u, 0u};
            const int col = (wh == 0) ? 0 : 129;
            dst[((n * 128 + h) * XT_W + col) * 4 + tid] = z;
        }
    }
}

// ---------------------------------------------------------------------------
// Main conv: zero LDS, zero barriers. Wave owns one 16-och tile of a
// (n, 8h x 64w) tile. Operand-swapped MFMA (A=pixels, B=weights): D row=pixel,
// col=och -> f32x4 stores. Stores are NON-TEMPORAL (bypass L2) so x_t stays
// L2-resident for the halo re-reads.
// ---------------------------------------------------------------------------
__global__ __launch_bounds__(256, 3)
void conv3x3_mfma(const unsigned short* __restrict__ xt,
                  const float* __restrict__ wk,
                  float* __restrict__ out) {
    const int hb = blockIdx.x, wh = blockIdx.y, n = blockIdx.z;
    const int H0 = hb * HT, W0 = wh * 64;
    const int lane = threadIdx.x & 63, wid = threadIdx.x >> 6;
    const int lq = lane >> 4, lr = lane & 15;

    // ---- weights -> registers (B operand): lane holds w_eff[och=wid*16+lr][c=lq*8+e]
    // Raw buffer index: ((c*3+ki)*3+kj)*64 + o   (reshape quirk).
    bf16x8 wB[9];
    #pragma unroll
    for (int p = 0; p < 9; ++p) {
        const int ki = p / 3, kj = p % 3;
        union { bf16x8 v; unsigned short s[8]; } u;
        #pragma unroll
        for (int j = 0; j < 8; ++j) {
            const int c = lq * 8 + j;
            u.s[j] = f2bf(wk[((c * 3 + ki) * 3 + kj) * 64 + wid * 16 + lr]);
        }
        wB[p] = u.v;
    }

    // ---- accumulators: 3-row ring x 4 pixel groups ----
    f32x4 acc[3][4];
    const f32x4 zero = {0.f, 0.f, 0.f, 0.f};
    #pragma unroll
    for (int a = 0; a < 3; ++a)
        #pragma unroll
        for (int pg = 0; pg < 4; ++pg) acc[a][pg] = zero;

    // per-thread output base (operand-swapped D): och = wid*16 + lr (col),
    // pixel = W0 + pg*16 + lq*4 + j (row) -> f32x4 over j.
    float* obase = out + ((size_t)(n * 64 + wid * 16 + lr) * 128) * 128 + W0 + lq * 4;

    // A-frag (pixels): lane holds x_t[pixel = W0+pg*16+lr+kj-1][c = lq*8..+7]
#define VOFF(PG, KJ) ((W0 + (PG) * 16 + lr + (KJ)) * 32 + lq * 8)

#define ROW(RHO)                                                              \
    {                                                                         \
        const int rg = H0 + (RHO) - 1;                                        \
        if ((unsigned)rg < 128u) {                                            \
            const unsigned short* rowp = xt + (size_t)(n * 128 + rg) * (XT_W * 32); \
            _Pragma("unroll")                                                 \
            for (int pg = 0; pg < 4; ++pg) {                                  \
                const bf16x8 fb0 = *(const bf16x8*)(rowp + VOFF(pg, 0));      \
                const bf16x8 fb1 = *(const bf16x8*)(rowp + VOFF(pg, 1));      \
                const bf16x8 fb2 = *(const bf16x8*)(rowp + VOFF(pg, 2));      \
                _Pragma("unroll")                                             \
                for (int ki = 0; ki < 3; ++ki) {                              \
                    if ((RHO) - ki < 0 || (RHO) - ki > HT - 1) continue;      \
                    const int a = ((RHO) - ki + 1) % 3;                       \
                    acc[a][pg] = __builtin_amdgcn_mfma_f32_16x16x32_bf16(     \
                        fb0, wB[ki * 3 + 0], acc[a][pg], 0, 0, 0);            \
                    acc[a][pg] = __builtin_amdgcn_mfma_f32_16x16x32_bf16(     \
                        fb1, wB[ki * 3 + 1], acc[a][pg], 0, 0, 0);            \
                    acc[a][pg] = __builtin_amdgcn_mfma_f32_16x16x32_bf16(     \
                        fb2, wB[ki * 3 + 2], acc[a][pg], 0, 0, 0);            \
                }                                                             \
            }                                                                 \
        }                                                                     \
        if ((RHO) >= 2) {                                                     \
            const int h = H0 + (RHO) - 2;                                     \
            const int a = ((RHO) - 1) % 3;                                    \
            _Pragma("unroll")                                                 \
            for (int pg = 0; pg < 4; ++pg) {                                  \
                __builtin_nontemporal_store(acc[a][pg],                       \
                    (f32x4*)(obase + h * 128 + pg * 16));                     \
                acc[a][pg] = zero;                                            \
            }                                                                 \
        }                                                                     \
    }

    ROW(0) ROW(1) ROW(2) ROW(3) ROW(4) ROW(5) ROW(6) ROW(7) ROW(8) ROW(9)
#undef ROW
#undef VOFF
}

extern "C" void kernel_launch(void* const* d_in, const int* in_sizes, int n_in,
                              void* d_out, int out_size, void* d_ws, size_t ws_size,
                              hipStream_t stream) {
    const float* x  = (const float*)d_in[0];
    const float* wk = (const float*)d_in[1];
    float* out = (float*)d_out;
    unsigned short* xt = (unsigned short*)d_ws;   // 32*128*130*32 bf16 = 32.5 MiB

    {   // pre-pass: NCHW f32 -> padded NHWC bf16 (+ zeroed border cols)
        dim3 grid(16, 2, 32);    // hb, wh, n  (same mapping as conv -> same XCD)
        nchw_to_nhwc_bf16<<<grid, dim3(256), 0, stream>>>(x, xt);
    }
    {   // main conv
        dim3 grid(16, 2, 32);    // hb, wh, n
        conv3x3_mfma<<<grid, dim3(256), 0, stream>>>(xt, wk, out);
    }
}

// Round 9
// 64.755 us; speedup vs baseline: 1.1006x; 1.1006x over previous
//
#include <hip/hip_runtime.h>

typedef __attribute__((ext_vector_type(8))) short   bf16x8;
typedef __attribute__((ext_vector_type(4))) float   f32x4;
typedef __attribute__((ext_vector_type(4))) unsigned int u32x4;

#define HT 8           // output rows per block (main kernel)
#define XT_W 130       // padded pixel stride: col 0 and col 129 are zero

__device__ __forceinline__ unsigned short f2bf(float f) {
    union { float f; unsigned u; } v; v.f = f;
    unsigned u = v.u;
    u += 0x7FFFu + ((u >> 16) & 1u);   // RNE
    return (unsigned short)(u >> 16);
}

// ---------------------------------------------------------------------------
// Pre-pass v2: barrier-free, LDS-free. One thread = one pixel: 32 independent
// stride-64KB loads (lanes run along w -> every load instr is a coalesced
// 256B segment), pack to bf16, store the 64B NHWC pixel directly.
// Blocks >= 2048 zero the border columns (p=0, p=129).
// ---------------------------------------------------------------------------
__global__ __launch_bounds__(256, 6)
void nchw_to_nhwc_bf16(const float* __restrict__ x, unsigned short* __restrict__ xt) {
    const int bid = blockIdx.x;
    if (bid < 2048) {
        const int p_lin = bid * 256 + threadIdx.x;       // n*16384 + h*128 + w
        const int n = p_lin >> 14, hw = p_lin & 16383;
        const int h = hw >> 7, w = hw & 127;

        const float* src = x + ((size_t)n * 524288 + hw);
        float v[32];
        #pragma unroll
        for (int c = 0; c < 32; ++c) v[c] = src[(size_t)c * 16384];

        u32x4 pk[4];
        #pragma unroll
        for (int q = 0; q < 4; ++q)
            #pragma unroll
            for (int e = 0; e < 4; ++e)
                pk[q][e] = (unsigned)f2bf(v[q * 8 + e * 2]) |
                           ((unsigned)f2bf(v[q * 8 + e * 2 + 1]) << 16);

        u32x4* dst = (u32x4*)(xt + ((size_t)(n * 128 + h) * XT_W + 1 + w) * 32);
        #pragma unroll
        for (int q = 0; q < 4; ++q) dst[q] = pk[q];
    } else {
        // border zeroing: 8192 border pixels (32n x 128h x 2 cols), 64B each
        const int idx = (bid - 2048) * 256 + threadIdx.x;
        const int n = idx >> 8, h = (idx >> 1) & 127;
        const int col = (idx & 1) ? (XT_W - 1) : 0;
        u32x4* dst = (u32x4*)(xt + ((size_t)(n * 128 + h) * XT_W + col) * 32);
        const u32x4 z = {0u, 0u, 0u, 0u};
        #pragma unroll
        for (int q = 0; q < 4; ++q) dst[q] = z;
    }
}

// ---------------------------------------------------------------------------
// Main conv (R6 verbatim): zero LDS, zero barriers, zero per-row OOB logic.
// Wave owns one 16-och tile of a (n, 8h x 64w) tile; B-frags load straight
// from x_t via SGPR row base + constant per-lane voffset.
// ---------------------------------------------------------------------------
__global__ __launch_bounds__(256, 4)
void conv3x3_mfma(const unsigned short* __restrict__ xt,
                  const float* __restrict__ wk,
                  float* __restrict__ out) {
    const int hb = blockIdx.x, wh = blockIdx.y, n = blockIdx.z;
    const int H0 = hb * HT, W0 = wh * 64;
    const int lane = threadIdx.x & 63, wid = threadIdx.x >> 6;
    const int lq = lane >> 4, lr = lane & 15;

    // ---- weights -> registers: wave `wid` owns och tile [wid*16, wid*16+16) ----
    // Raw buffer index: ((c*3+ki)*3+kj)*64 + o   (reshape quirk).
    bf16x8 wA[9];
    #pragma unroll
    for (int p = 0; p < 9; ++p) {
        const int ki = p / 3, kj = p % 3;
        union { bf16x8 v; unsigned short s[8]; } u;
        #pragma unroll
        for (int j = 0; j < 8; ++j) {
            const int c = lq * 8 + j;
            u.s[j] = f2bf(wk[((c * 3 + ki) * 3 + kj) * 64 + wid * 16 + lr]);
        }
        wA[p] = u.v;
    }

    // ---- accumulators: 3-row ring x 4 pixel groups ----
    f32x4 acc[3][4];
    const f32x4 zero = {0.f, 0.f, 0.f, 0.f};
    #pragma unroll
    for (int a = 0; a < 3; ++a)
        #pragma unroll
        for (int pg = 0; pg < 4; ++pg) acc[a][pg] = zero;

    // per-thread output base: o = wid*16 + lq*4 (+j), w = W0 + lr (+pg*16)
    float* obase = out + (((size_t)(n * 64 + wid * 16 + lq * 4) * 128) * 128) + W0 + lr;

    // per-lane constant element offsets within a row: pixel p = W0+pg*16+lr+kj
#define VOFF(PG, KJ) ((W0 + (PG) * 16 + lr + (KJ)) * 32 + lq * 8)

#define ROW(RHO)                                                              \
    {                                                                         \
        const int rg = H0 + (RHO) - 1;                                        \
        if ((unsigned)rg < 128u) {                                            \
            const unsigned short* rowp = xt + (size_t)(n * 128 + rg) * (XT_W * 32); \
            _Pragma("unroll")                                                 \
            for (int pg = 0; pg < 4; ++pg) {                                  \
                const bf16x8 fb0 = *(const bf16x8*)(rowp + VOFF(pg, 0));      \
                const bf16x8 fb1 = *(const bf16x8*)(rowp + VOFF(pg, 1));      \
                const bf16x8 fb2 = *(const bf16x8*)(rowp + VOFF(pg, 2));      \
                _Pragma("unroll")                                             \
                for (int ki = 0; ki < 3; ++ki) {                              \
                    if ((RHO) - ki < 0 || (RHO) - ki > HT - 1) continue;      \
                    const int a = ((RHO) - ki + 1) % 3;                       \
                    acc[a][pg] = __builtin_amdgcn_mfma_f32_16x16x32_bf16(     \
                        wA[ki * 3 + 0], fb0, acc[a][pg], 0, 0, 0);            \
                    acc[a][pg] = __builtin_amdgcn_mfma_f32_16x16x32_bf16(     \
                        wA[ki * 3 + 1], fb1, acc[a][pg], 0, 0, 0);            \
                    acc[a][pg] = __builtin_amdgcn_mfma_f32_16x16x32_bf16(     \
                        wA[ki * 3 + 2], fb2, acc[a][pg], 0, 0, 0);            \
                }                                                             \
            }                                                                 \
        }                                                                     \
        if ((RHO) >= 2) {                                                     \
            const int h = H0 + (RHO) - 2;                                     \
            const int a = ((RHO) - 1) % 3;                                    \
            _Pragma("unroll")                                                 \
            for (int pg = 0; pg < 4; ++pg) {                                  \
                _Pragma("unroll")                                             \
                for (int j = 0; j < 4; ++j)                                   \
                    obase[(j * 128 + h) * 128 + pg * 16] = acc[a][pg][j];     \
                acc[a][pg] = zero;                                            \
            }                                                                 \
        }                                                                     \
    }

    ROW(0) ROW(1) ROW(2) ROW(3) ROW(4) ROW(5) ROW(6) ROW(7) ROW(8) ROW(9)
#undef ROW
#undef VOFF
}

extern "C" void kernel_launch(void* const* d_in, const int* in_sizes, int n_in,
                              void* d_out, int out_size, void* d_ws, size_t ws_size,
                              hipStream_t stream) {
    const float* x  = (const float*)d_in[0];
    const float* wk = (const float*)d_in[1];
    float* out = (float*)d_out;
    unsigned short* xt = (unsigned short*)d_ws;   // 32*128*130*32 bf16 = 32.5 MiB

    {   // pre-pass v2: barrier-free NCHW f32 -> padded NHWC bf16
        nchw_to_nhwc_bf16<<<dim3(2048 + 32), dim3(256), 0, stream>>>(x, xt);
    }
    {   // main conv
        dim3 grid(16, 2, 32);    // hb, wh, n  -> 1024 blocks
        conv3x3_mfma<<<grid, dim3(256), 0, stream>>>(xt, wk, out);
    }
}

// Round 10
// 44.541 us; speedup vs baseline: 1.6000x; 1.4538x over previous
//
#include <hip/hip_runtime.h>

typedef __attribute__((ext_vector_type(8))) short   bf16x8;
typedef __attribute__((ext_vector_type(4))) float   f32x4;
typedef __attribute__((ext_vector_type(4))) unsigned int u32x4;

#define HT    8        // output rows per block
#define WSPAN 66       // staged w columns: 64 + 2 halo
#define NR    10       // staged rows: HT + 2

__device__ __forceinline__ unsigned short f2bf(float f) {
    union { float f; unsigned u; } v; v.f = f;
    unsigned u = v.u;
    u += 0x7FFFu + ((u >> 16) & 1u);   // RNE
    return (unsigned short)(u >> 16);
}

// Fused conv: stage the block's whole 10x66x32 input tile to LDS (bf16,
// zero-filled OOB) with NO barriers, ONE __syncthreads(), then barrier-free
// MFMA compute with the acc ring. 42.2 KB LDS -> 3 blocks/CU.
__global__ __launch_bounds__(256, 3)
void conv3x3_fused(const float* __restrict__ x, const float* __restrict__ wk,
                   float* __restrict__ out) {
    const int hb = blockIdx.x, wh = blockIdx.y, n = blockIdx.z;
    const int H0 = hb * HT, W0 = wh * 64;
    const int tid  = threadIdx.x;
    const int lane = tid & 63, wid = tid >> 6;
    const int lq = lane >> 4, lr = lane & 15;

    __shared__ u32x4 lds[NR * WSPAN * 4];   // 42,240 B

    // ---- staging tasks ----
    // task A: every thread: (cb = tid>>6, wq = tid&63)
    // task B: threads 0..7: (cb = tid>>1, wq = 64+(tid&1))
    const int cb0 = tid >> 6, wq0 = tid & 63;
    const bool hasB = (tid < 8);
    const int cb1 = tid >> 1, wq1 = 64 + (tid & 1);

    auto issue_loads = [&](int rg, int cb, int wq, float (&dst)[8]) {
        const int wg = W0 - 1 + wq;
        const bool ok = ((unsigned)rg < 128u) && ((unsigned)wg < 128u);
        const float* p = x + (((n * 32 + cb * 8) * 128 + rg) * 128 + wg);
        #pragma unroll
        for (int j = 0; j < 8; ++j)
            dst[j] = ok ? p[j * 16384] : 0.0f;   // channel stride = H*W
    };
    // swizzle f=(wq>>1)&3: measured conflict-free in R3 (SQ_LDS_BANK_CONFLICT=0)
    auto lds_write = [&](int row, int cb, int wq, const float (&src)[8]) {
        const int f = (wq >> 1) & 3;
        u32x4 pk;
        pk[0] = (unsigned)f2bf(src[0]) | ((unsigned)f2bf(src[1]) << 16);
        pk[1] = (unsigned)f2bf(src[2]) | ((unsigned)f2bf(src[3]) << 16);
        pk[2] = (unsigned)f2bf(src[4]) | ((unsigned)f2bf(src[5]) << 16);
        pk[3] = (unsigned)f2bf(src[6]) | ((unsigned)f2bf(src[7]) << 16);
        lds[(row * WSPAN + wq) * 4 + (cb ^ f)] = pk;
    };
    auto frag_read = [&](int row, int wq) -> bf16x8 {
        const int f = (wq >> 1) & 3;
        union { u32x4 u; bf16x8 v; } cv;
        cv.u = lds[(row * WSPAN + wq) * 4 + (lq ^ f)];
        return cv.v;
    };

    // ---- stage all NR rows, 2-deep register pipeline, zero barriers ----
    float bufA[2][8], bufB[2][8];
    issue_loads(H0 - 1, cb0, wq0, bufA[0]);
    if (hasB) issue_loads(H0 - 1, cb1, wq1, bufB[0]);
    issue_loads(H0, cb0, wq0, bufA[1]);
    if (hasB) issue_loads(H0, cb1, wq1, bufB[1]);

#define STAGE(R)                                                              \
    {                                                                         \
        lds_write((R), cb0, wq0, bufA[(R) & 1]);                              \
        if (hasB) lds_write((R), cb1, wq1, bufB[(R) & 1]);                    \
        if ((R) + 2 < NR) {                                                   \
            issue_loads(H0 + (R) + 1, cb0, wq0, bufA[(R) & 1]);               \
            if (hasB) issue_loads(H0 + (R) + 1, cb1, wq1, bufB[(R) & 1]);     \
        }                                                                     \
    }
    STAGE(0) STAGE(1) STAGE(2) STAGE(3) STAGE(4)
    STAGE(5) STAGE(6) STAGE(7) STAGE(8) STAGE(9)
#undef STAGE

    // ---- weights -> registers: wave `wid` owns och tile [wid*16, wid*16+16) ----
    // Raw buffer index: ((c*3+ki)*3+kj)*64 + o   (reshape quirk).
    bf16x8 wA[9];
    #pragma unroll
    for (int p = 0; p < 9; ++p) {
        const int ki = p / 3, kj = p % 3;
        union { bf16x8 v; unsigned short s[8]; } u;
        #pragma unroll
        for (int j = 0; j < 8; ++j) {
            const int c = lq * 8 + j;
            u.s[j] = f2bf(wk[((c * 3 + ki) * 3 + kj) * 64 + wid * 16 + lr]);
        }
        wA[p] = u.v;
    }

    __syncthreads();   // the ONLY barrier

    // ---- accumulators: 3-row ring x 4 pixel groups ----
    f32x4 acc[3][4];
    const f32x4 zero = {0.f, 0.f, 0.f, 0.f};
    #pragma unroll
    for (int a = 0; a < 3; ++a)
        #pragma unroll
        for (int pg = 0; pg < 4; ++pg) acc[a][pg] = zero;

    // per-thread output base: o = wid*16 + lq*4 (+j), w = W0 + lr (+pg*16)
    float* obase = out + (((size_t)(n * 64 + wid * 16 + lq * 4) * 128) * 128) + W0 + lr;

    // staged row RHO (zero-filled if OOB) feeds h = H0+RHO-ki; row h completes
    // at RHO = h-H0+2. All indices literal.
#define ROW(RHO)                                                              \
    {                                                                         \
        _Pragma("unroll")                                                     \
        for (int pg = 0; pg < 4; ++pg) {                                      \
            const bf16x8 fb0 = frag_read((RHO), pg * 16 + lr + 0);            \
            const bf16x8 fb1 = frag_read((RHO), pg * 16 + lr + 1);            \
            const bf16x8 fb2 = frag_read((RHO), pg * 16 + lr + 2);            \
            _Pragma("unroll")                                                 \
            for (int ki = 0; ki < 3; ++ki) {                                  \
                if ((RHO) - ki < 0 || (RHO) - ki > HT - 1) continue;          \
                const int a = ((RHO) - ki + 1) % 3;                           \
                acc[a][pg] = __builtin_amdgcn_mfma_f32_16x16x32_bf16(         \
                    wA[ki * 3 + 0], fb0, acc[a][pg], 0, 0, 0);                \
                acc[a][pg] = __builtin_amdgcn_mfma_f32_16x16x32_bf16(         \
                    wA[ki * 3 + 1], fb1, acc[a][pg], 0, 0, 0);                \
                acc[a][pg] = __builtin_amdgcn_mfma_f32_16x16x32_bf16(         \
                    wA[ki * 3 + 2], fb2, acc[a][pg], 0, 0, 0);                \
            }                                                                 \
        }                                                                     \
        if ((RHO) >= 2) {                                                     \
            const int h = H0 + (RHO) - 2;                                     \
            const int a = ((RHO) - 1) % 3;                                    \
            _Pragma("unroll")                                                 \
            for (int pg = 0; pg < 4; ++pg) {                                  \
                _Pragma("unroll")                                             \
                for (int j = 0; j < 4; ++j)                                   \
                    obase[(j * 128 + h) * 128 + pg * 16] = acc[a][pg][j];     \
                acc[a][pg] = zero;                                            \
            }                                                                 \
        }                                                                     \
    }

    ROW(0) ROW(1) ROW(2) ROW(3) ROW(4) ROW(5) ROW(6) ROW(7) ROW(8) ROW(9)
#undef ROW
}

extern "C" void kernel_launch(void* const* d_in, const int* in_sizes, int n_in,
                              void* d_out, int out_size, void* d_ws, size_t ws_size,
                              hipStream_t stream) {
    const float* x  = (const float*)d_in[0];
    const float* wk = (const float*)d_in[1];
    float* out = (float*)d_out;
    dim3 grid(16, 2, 32);   // hb, wh, n  -> 1024 blocks
    dim3 block(256);
    conv3x3_fused<<<grid, block, 0, stream>>>(x, wk, out);
}

// Round 11
// 43.175 us; speedup vs baseline: 1.6507x; 1.0316x over previous
//
#include <hip/hip_runtime.h>

typedef __attribute__((ext_vector_type(8))) short   bf16x8;
typedef __attribute__((ext_vector_type(4))) float   f32x4;
typedef __attribute__((ext_vector_type(4))) unsigned int u32x4;

#define HT    8        // output rows per block
#define WT    32       // output w columns per block
#define WSPAN 34       // staged w columns: WT + 2 halo
#define NR    10       // staged rows: HT + 2

__device__ __forceinline__ unsigned short f2bf(float f) {
    union { float f; unsigned u; } v; v.f = f;
    unsigned u = v.u;
    u += 0x7FFFu + ((u >> 16) & 1u);   // RNE
    return (unsigned short)(u >> 16);
}

// Fused conv, 32-wide tiles: stage the 10x34x32 input tile to LDS (bf16,
// zero-filled OOB) with NO barriers, ONE __syncthreads(), then barrier-free
// MFMA compute. 21.8 KB LDS + ~100 regs -> 4+ blocks/CU, phase-staggered.
__global__ __launch_bounds__(256, 4)
void conv3x3_fused(const float* __restrict__ x, const float* __restrict__ wk,
                   float* __restrict__ out) {
    const int hb = blockIdx.x, wq4 = blockIdx.y, n = blockIdx.z;
    const int H0 = hb * HT, W0 = wq4 * WT;
    const int tid  = threadIdx.x;
    const int lane = tid & 63, wid = tid >> 6;
    const int lq = lane >> 4, lr = lane & 15;

    __shared__ u32x4 lds[NR * WSPAN * 4];   // 21,760 B

    // ---- staging task: 136 tasks/row (34 wq x 4 c-octets), threads 0..135 ----
    const bool act = (tid < 136);
    const int cb = (tid < 128) ? (tid >> 5) : ((tid - 128) >> 1);
    const int wq = (tid < 128) ? (tid & 31) : (32 + ((tid - 128) & 1));

    auto issue_loads = [&](int rg, float (&dst)[8]) {
        const int wg = W0 - 1 + wq;
        const bool ok = act && ((unsigned)rg < 128u) && ((unsigned)wg < 128u);
        const float* p = x + (((n * 32 + cb * 8) * 128 + rg) * 128 + wg);
        #pragma unroll
        for (int j = 0; j < 8; ++j)
            dst[j] = ok ? p[j * 16384] : 0.0f;   // channel stride = H*W
    };
    // swizzle f=(wq>>1)&3: measured conflict-free (R3/R10: SQ_LDS_BANK_CONFLICT=0)
    auto lds_write = [&](int row, const float (&src)[8]) {
        if (!act) return;
        const int f = (wq >> 1) & 3;
        u32x4 pk;
        pk[0] = (unsigned)f2bf(src[0]) | ((unsigned)f2bf(src[1]) << 16);
        pk[1] = (unsigned)f2bf(src[2]) | ((unsigned)f2bf(src[3]) << 16);
        pk[2] = (unsigned)f2bf(src[4]) | ((unsigned)f2bf(src[5]) << 16);
        pk[3] = (unsigned)f2bf(src[6]) | ((unsigned)f2bf(src[7]) << 16);
        lds[(row * WSPAN + wq) * 4 + (cb ^ f)] = pk;
    };
    auto frag_read = [&](int row, int w) -> bf16x8 {
        const int f = (w >> 1) & 3;
        union { u32x4 u; bf16x8 v; } cv;
        cv.u = lds[(row * WSPAN + w) * 4 + (lq ^ f)];
        return cv.v;
    };

    // ---- stage all NR rows, 2-deep register pipeline, zero barriers ----
    float buf[2][8];
    issue_loads(H0 - 1, buf[0]);
    issue_loads(H0,     buf[1]);

#define STAGE(R)                                                              \
    {                                                                         \
        lds_write((R), buf[(R) & 1]);                                         \
        if ((R) + 2 < NR) issue_loads(H0 + (R) + 1, buf[(R) & 1]);            \
    }
    STAGE(0) STAGE(1) STAGE(2) STAGE(3) STAGE(4)
    STAGE(5) STAGE(6) STAGE(7) STAGE(8) STAGE(9)
#undef STAGE

    // ---- weights -> registers: wave `wid` owns och tile [wid*16, wid*16+16) ----
    // Raw buffer index: ((c*3+ki)*3+kj)*64 + o   (reshape quirk).
    bf16x8 wA[9];
    #pragma unroll
    for (int p = 0; p < 9; ++p) {
        const int ki = p / 3, kj = p % 3;
        union { bf16x8 v; unsigned short s[8]; } u;
        #pragma unroll
        for (int j = 0; j < 8; ++j) {
            const int c = lq * 8 + j;
            u.s[j] = f2bf(wk[((c * 3 + ki) * 3 + kj) * 64 + wid * 16 + lr]);
        }
        wA[p] = u.v;
    }

    __syncthreads();   // the ONLY barrier

    // ---- accumulators: 3-row ring x 2 pixel groups ----
    f32x4 acc[3][2];
    const f32x4 zero = {0.f, 0.f, 0.f, 0.f};
    #pragma unroll
    for (int a = 0; a < 3; ++a)
        #pragma unroll
        for (int pg = 0; pg < 2; ++pg) acc[a][pg] = zero;

    // per-thread output base: o = wid*16 + lq*4 (+j), w = W0 + lr (+pg*16)
    float* obase = out + (((size_t)(n * 64 + wid * 16 + lq * 4) * 128) * 128) + W0 + lr;

    // staged row RHO (zero-filled if OOB) feeds h = H0+RHO-ki; row h completes
    // at RHO = h-H0+2. All indices literal.
#define ROW(RHO)                                                              \
    {                                                                         \
        _Pragma("unroll")                                                     \
        for (int pg = 0; pg < 2; ++pg) {                                      \
            const bf16x8 fb0 = frag_read((RHO), pg * 16 + lr + 0);            \
            const bf16x8 fb1 = frag_read((RHO), pg * 16 + lr + 1);            \
            const bf16x8 fb2 = frag_read((RHO), pg * 16 + lr + 2);            \
            _Pragma("unroll")                                                 \
            for (int ki = 0; ki < 3; ++ki) {                                  \
                if ((RHO) - ki < 0 || (RHO) - ki > HT - 1) continue;          \
                const int a = ((RHO) - ki + 1) % 3;                           \
                acc[a][pg] = __builtin_amdgcn_mfma_f32_16x16x32_bf16(         \
                    wA[ki * 3 + 0], fb0, acc[a][pg], 0, 0, 0);                \
                acc[a][pg] = __builtin_amdgcn_mfma_f32_16x16x32_bf16(         \
                    wA[ki * 3 + 1], fb1, acc[a][pg], 0, 0, 0);                \
                acc[a][pg] = __builtin_amdgcn_mfma_f32_16x16x32_bf16(         \
                    wA[ki * 3 + 2], fb2, acc[a][pg], 0, 0, 0);                \
            }                                                                 \
        }                                                                     \
        if ((RHO) >= 2) {                                                     \
            const int h = H0 + (RHO) - 2;                                     \
            const int a = ((RHO) - 1) % 3;                                    \
            _Pragma("unroll")                                                 \
            for (int pg = 0; pg < 2; ++pg) {                                  \
                _Pragma("unroll")                                             \
                for (int j = 0; j < 4; ++j)                                   \
                    obase[(j * 128 + h) * 128 + pg * 16] = acc[a][pg][j];     \
                acc[a][pg] = zero;                                            \
            }                                                                 \
        }                                                                     \
    }

    ROW(0) ROW(1) ROW(2) ROW(3) ROW(4) ROW(5) ROW(6) ROW(7) ROW(8) ROW(9)
#undef ROW
}

extern "C" void kernel_launch(void* const* d_in, const int* in_sizes, int n_in,
                              void* d_out, int out_size, void* d_ws, size_t ws_size,
                              hipStream_t stream) {
    const float* x  = (const float*)d_in[0];
    const float* wk = (const float*)d_in[1];
    float* out = (float*)d_out;
    dim3 grid(16, 4, 32);   // hb, w-quarter, n  -> 2048 blocks
    dim3 block(256);
    conv3x3_fused<<<grid, block, 0, stream>>>(x, wk, out);
}